// Round 11
// baseline (330.064 us; speedup 1.0000x reference)
//
#include <hip/hip_runtime.h>

// AliasFreeActivation fused kernel, round 11: B and C phases on MFMA.
//   GEMM1: act^T = t1^T @ FB^T   (M=u:80, K=r:32, N=v:80)  mfma_f32_16x16x32_bf16
//   GEMM2: t2^T  = GC^T @ act^T  (M=o:32, K=u:96, N=v:80)
//   act^T stays in registers: GEMM1 D-fragment (row=4q+ri, col=n16) has the
//   same lane mapping as GEMM2's B-operand (k=4q+j, n=n16) -> chain directly
//   with in-register bias+leaky+bf16 pack. A (h-up) and D (v-down, f16 dot2)
//   stay on VALU (r10-verified).
// Fragment layouts (per verified guide facts m89/m91/m156/m162):
//   A[i][k]: i=l&15, k=4*(l>>4)+j (j=0..3 regs 0-1), k+16 (regs 2-3)
//   B[k][n]: n=l&15, same k pattern; D[r][c]: c=l&15, r=4*(l>>4)+reg.
// LDS (bytes): t1T bf16[80][36] @0 | FBm bf16[80][36] @5760 |
//              GCm bf16[32][100] @11520 | t2t f16[32][88] @17920. = 23552 B
// Zero-pad: t1T cols 26..35 = 0; FBm r>=26 or v>=74 = 0; GCm out-of-window = 0
// (u>=74 auto-zero since 2o+11<=73). Garbage t2t cols 74..87 never read by D.

typedef float f4 __attribute__((ext_vector_type(4)));
typedef short s8v __attribute__((ext_vector_type(8)));
typedef _Float16 h2 __attribute__((ext_vector_type(2)));

#define T1T_OFF 0
#define FB_OFF  5760
#define GC_OFF  11520
#define T2T_OFF 17920
#define T2T_SB  176
#define LDS_B   23552

union U8 { s8v s; uint4 u; };

static __device__ __forceinline__ unsigned cvtpk_bf16(float lo, float hi) {
    unsigned r;
    asm("v_cvt_pk_bf16_f32 %0, %1, %2" : "=v"(r) : "v"(lo), "v"(hi));
    return r;
}
static __device__ __forceinline__ unsigned short bf16_1(float x) {
    return (unsigned short)cvtpk_bf16(x, x);
}
static __device__ __forceinline__ h2 as_h2(unsigned u) {
    union { unsigned u; h2 h; } x; x.u = u; return x.h;
}
#define LEAKY(x) ((x) * 0.6f + 0.4f * __builtin_fabsf(x))

__global__ __launch_bounds__(256, 4) void afa_kernel(
    const float* __restrict__ x, const float* __restrict__ bias,
    const float* __restrict__ fup, const float* __restrict__ fdn,
    float* __restrict__ out)
{
    __shared__ __align__(16) unsigned char smem[LDS_B];

    const int tid   = threadIdx.x;
    const int blk   = blockIdx.x;
    const int plane = blk >> 6;
    const int tile  = blk & 63;
    const int ty = tile >> 3, tx = tile & 7;
    const bool edge = (tx == 7) || (ty == 7);

    float fr[24], gr[12];
    #pragma unroll
    for (int i = 0; i < 24; ++i) fr[i] = fup[i];
    #pragma unroll
    for (int i = 0; i < 12; ++i) gr[i] = fdn[i];

    // dot2 filter pairs for D: gpk[m] = (g[11-2m], g[10-2m])
    h2 gpk[6];
    #pragma unroll
    for (int m = 0; m < 6; ++m) {
        h2 p;
        p.x = (_Float16)gr[11 - 2 * m];
        p.y = (_Float16)gr[10 - 2 * m];
        gpk[m] = p;
    }

    // bias fold: act += b*s[k0(u)]*s[k0(v)], s[p]=sum_t f[p+4t]
    const float s0 = fr[0] + fr[4] + fr[8]  + fr[12] + fr[16] + fr[20];
    const float s1 = fr[1] + fr[5] + fr[9]  + fr[13] + fr[17] + fr[21];
    const float s2 = fr[2] + fr[6] + fr[10] + fr[14] + fr[18] + fr[22];
    const float s3 = fr[3] + fr[7] + fr[11] + fr[15] + fr[19] + fr[23];
    const float b  = bias[plane & 255];

    const int iy_base = 16 * ty + 1;
    const int ix_base = 16 * tx + 1;
    const float* xp = x + (size_t)plane * (128 * 128);

    // ---- fills (disjoint LDS regions; same barrier as A) ----
    // FBm[v][r] = f[k0(v)+4t] with t=base(v)-r (0..5), base(v)=5+((v+1)>>2)
    for (int e = tid; e < 2560; e += 256) {
        const int v = e >> 5, r = e & 31;
        float val = 0.f;
        if (v < 74 && r < 26) {
            const int k0 = (v + 1) & 3;
            const int t  = 5 + ((v + 1) >> 2) - r;
            if (t >= 0 && t <= 5) val = fup[k0 + 4 * t];
        }
        *(unsigned short*)(smem + FB_OFF + (v * 36 + r) * 2) = bf16_1(val);
    }
    // GCm[o][u] = g[2o+11-u] (valid window), cols 96..99 pad zero
    {
        const int o = tid >> 3, c0 = tid & 7;
        #pragma unroll
        for (int ci = 0; ci < 13; ++ci) {
            const int c = c0 + 8 * ci;
            if (c < 100) {
                const int idx = 2 * o + 11 - c;
                const float val = (idx >= 0 && idx < 12) ? fdn[idx] : 0.f;
                *(unsigned short*)(smem + GC_OFF + (o * 100 + c) * 2) = bf16_1(val);
            }
        }
    }
    // t1T pad cols 26..35 (dwords 13..17 of each 36-half row) = 0
    if (tid < 80) {
        unsigned* pz = (unsigned*)(smem + T1T_OFF + tid * 72 + 52);
        #pragma unroll
        for (int j = 0; j < 5; ++j) pz[j] = 0u;
    }

    // ---- A: horizontal upsample (f32 VALU) -> t1T bf16 [u][r] ----
    for (int task = tid; task < 260; task += 256) {
        const int r = task / 10, ug = task - r * 10;
        float xw[8];
        if (!edge) {
            const float* row = xp + (iy_base + r) * 128 + (ix_base + 2 * ug);
            #pragma unroll
            for (int m = 0; m < 8; ++m) xw[m] = row[m];
        } else {
            const int iy = min(iy_base + r, 127);
            const float* row = xp + iy * 128;
            const int ix0 = ix_base + 2 * ug;
            #pragma unroll
            for (int m = 0; m < 8; ++m) xw[m] = row[min(ix0 + m, 127)];
        }
        #pragma unroll
        for (int du = 0; du < 8; ++du) {
            const int k0 = (du + 1) & 3;
            const int bb = ((du + 25 - k0) >> 2) - 1;
            float acc = 0.f;
            #pragma unroll
            for (int t = 0; t < 6; ++t) acc += fr[k0 + 4 * t] * xw[bb - t];
            const int u = 8 * ug + du;
            *(unsigned short*)(smem + T1T_OFF + (u * 36 + r) * 2) = bf16_1(acc);
        }
    }
    __syncthreads();

    // ---- GEMM1 -> bias+leaky -> GEMM2 (register-chained) ----
    {
        const int lane = tid & 63, wid = tid >> 6;
        const int q = lane >> 4, n16 = lane & 15;

        U8 t1A[5];
        #pragma unroll
        for (int mt = 0; mt < 5; ++mt) {
            const unsigned char* p = smem + T1T_OFF + ((n16 + 16 * mt) * 36 + 4 * q) * 2;
            const uint2 lo = *(const uint2*)p;
            const uint2 hi = *(const uint2*)(p + 32);
            t1A[mt].u = uint4{lo.x, lo.y, hi.x, hi.y};
        }
        U8 gcA[2][3];
        #pragma unroll
        for (int mt2 = 0; mt2 < 2; ++mt2)
            #pragma unroll
            for (int kt = 0; kt < 3; ++kt) {
                const unsigned char* p =
                    smem + GC_OFF + ((n16 + 16 * mt2) * 100 + 32 * kt + 4 * q) * 2;
                const uint2 lo = *(const uint2*)p;
                const uint2 hi = *(const uint2*)(p + 32);
                gcA[mt2][kt].u = uint4{lo.x, lo.y, hi.x, hi.y};
            }

        // bias terms: k0(u)=(ri+1)&3 (lane-invariant), k0(v)=(n16+1)&3
        const int kv = (n16 + 1) & 3;
        const float sv = (kv == 0) ? s0 : (kv == 1) ? s1 : (kv == 2) ? s2 : s3;
        const float tm0 = b * s1 * sv, tm1 = b * s2 * sv;
        const float tm2 = b * s3 * sv, tm3 = b * s0 * sv;
        const f4 zero = {0.f, 0.f, 0.f, 0.f};

        const int nits = (wid == 0) ? 2 : 1;
        for (int ni = 0; ni < nits; ++ni) {
            const int nt = (ni == 0) ? wid : 4;
            U8 fbB;
            {
                const unsigned char* p =
                    smem + FB_OFF + ((n16 + 16 * nt) * 36 + 4 * q) * 2;
                const uint2 lo = *(const uint2*)p;
                const uint2 hi = *(const uint2*)(p + 32);
                fbB.u = uint4{lo.x, lo.y, hi.x, hi.y};
            }
            // GEMM1: act^T tiles, u = 4q+ri+16mt, v = n16+16nt
            f4 acc1[5];
            #pragma unroll
            for (int mt = 0; mt < 5; ++mt)
                acc1[mt] = __builtin_amdgcn_mfma_f32_16x16x32_bf16(
                    t1A[mt].s, fbB.s, zero, 0, 0, 0);
            // bias + leaky + pack -> GEMM2 B-fragments (k=u)
            U8 bfrag[3];
            #pragma unroll
            for (int kt = 0; kt < 2; ++kt) {
                const f4 a0 = acc1[2 * kt], a1 = acc1[2 * kt + 1];
                const float e0 = LEAKY(a0[0] + tm0), e1 = LEAKY(a0[1] + tm1);
                const float e2 = LEAKY(a0[2] + tm2), e3 = LEAKY(a0[3] + tm3);
                const float f0 = LEAKY(a1[0] + tm0), f1 = LEAKY(a1[1] + tm1);
                const float f2 = LEAKY(a1[2] + tm2), f3 = LEAKY(a1[3] + tm3);
                bfrag[kt].u = uint4{cvtpk_bf16(e0, e1), cvtpk_bf16(e2, e3),
                                    cvtpk_bf16(f0, f1), cvtpk_bf16(f2, f3)};
            }
            {
                const f4 a0 = acc1[4];   // u=64..79 real; u=80..95 zero
                const float e0 = LEAKY(a0[0] + tm0), e1 = LEAKY(a0[1] + tm1);
                const float e2 = LEAKY(a0[2] + tm2), e3 = LEAKY(a0[3] + tm3);
                bfrag[2].u = uint4{cvtpk_bf16(e0, e1), cvtpk_bf16(e2, e3), 0u, 0u};
            }
            // GEMM2: t2^T tiles, o = 4q+ri+16mt2
            f4 acc2[2] = {zero, zero};
            #pragma unroll
            for (int mt2 = 0; mt2 < 2; ++mt2)
                #pragma unroll
                for (int kt = 0; kt < 3; ++kt)
                    acc2[mt2] = __builtin_amdgcn_mfma_f32_16x16x32_bf16(
                        gcA[mt2][kt].s, bfrag[kt].s, acc2[mt2], 0, 0, 0);
            // write t2t[o][v] f16
            #pragma unroll
            for (int mt2 = 0; mt2 < 2; ++mt2)
                #pragma unroll
                for (int ri = 0; ri < 4; ++ri) {
                    const int o = 4 * q + ri + 16 * mt2;
                    *(_Float16*)(smem + T2T_OFF + (o * 88 + n16 + 16 * nt) * 2)
                        = (_Float16)acc2[mt2][ri];
                }
        }
    }
    __syncthreads();

    // ---- D: vertical downsample via dot2 (r10-verified), *sqrt2, store ----
    {
        const int oy0 = ty * 32, ox0 = tx * 32;
        float* op = out + (size_t)plane * (236 * 236);
        const int ox = tid & 31, g = tid >> 5;
        const unsigned* tr = (const unsigned*)(smem + T2T_OFF + ox * T2T_SB + 16 * g);
        const uint4 q0 = *(const uint4*)(tr);
        const uint4 q1 = *(const uint4*)(tr + 4);
        const unsigned dl = tr[8];
        unsigned d[9] = {q0.x, q0.y, q0.z, q0.w, q1.x, q1.y, q1.z, q1.w, dl};
        const int oxg = ox0 + ox;
        if (!edge) {
            #pragma unroll
            for (int dv = 0; dv < 4; ++dv) {
                float acc = 0.f;
                #pragma unroll
                for (int m = 0; m < 6; ++m)
                    acc = __builtin_amdgcn_fdot2(as_h2(d[dv + m]), gpk[m], acc, false);
                op[(oy0 + 4 * g + dv) * 236 + oxg] = acc * 1.4142135623730951f;
            }
        } else {
            #pragma unroll
            for (int dv = 0; dv < 4; ++dv) {
                float acc = 0.f;
                #pragma unroll
                for (int m = 0; m < 6; ++m)
                    acc = __builtin_amdgcn_fdot2(as_h2(d[dv + m]), gpk[m], acc, false);
                const int oy = oy0 + 4 * g + dv;
                if (oy < 236 && oxg < 236)
                    op[oy * 236 + oxg] = acc * 1.4142135623730951f;
            }
        }
    }
}

extern "C" void kernel_launch(void* const* d_in, const int* in_sizes, int n_in,
                              void* d_out, int out_size, void* d_ws, size_t ws_size,
                              hipStream_t stream) {
    const float* x    = (const float*)d_in[0];
    const float* bias = (const float*)d_in[1];
    const float* fup  = (const float*)d_in[2];
    const float* fdn  = (const float*)d_in[3];
    float* out = (float*)d_out;

    dim3 grid(1024 * 64);
    dim3 block(256);
    afa_kernel<<<grid, block, 0, stream>>>(x, bias, fup, fdn, out);
}

// Round 13
// 206.429 us; speedup vs baseline: 1.5989x; 1.5989x over previous
//
#include <hip/hip_runtime.h>

// AliasFreeActivation fused kernel, round 13 (= r12 with the sqrt2 bug fixed:
// gpk is shared by C and D, so folding sqrt2 into it applied it twice;
// reverted to sqrt2 in D's epilogue only).
//  - LDS 20160 B (act stride 80 halfs, t1 stride 80 words) -> 8 blocks/CU,
//    launch_bounds(256,8)
//  - leaky applied in packed f16 AFTER pkrtz: max(x, 0.2x) via v_pk_mul/max_f16
//  - keeps r10: direct-global A, bias fold, f16 act/t2t, dot2 C/D, edge paths
//
// Math (verified rounds 1-10):
//  A  h-up:   t1[r][u]=sum_t f[k0+4t]*xw[bb-t], u=8ug+du, k0=(du+1)&3,
//             bb=((du+25-k0)>>2)-1, window x cols [2ug,2ug+7]. No bias.
//  B  v-up:   act[v][:]=leaky( sum_t f[k0+4t]*w[bb-t][:] + bc[k0] );
//             v=8vt8+dv (<74), k0=(dv+1)&3, bb=5+((dv+1)>>2), w[m]=t1[2vt8+m].
//  C  h-down: t2t[o][v]=sum_k g[k]*act[v][2o+11-k] = sum_m dot2(actdw[i+m],gpk[m])
//             for o=8otg+i, window dwords [8otg..8otg+12].
//  D  v-down: out[4g+dv][ox]=sqrt2*sum_m dot2(t2tdw[dv+m],gpk[m]),
//             window t2t dwords [4g..4g+8].
//
// LDS (bytes): act f16 74x80 @0 (11840) | t1 f32 26x80w @11840 (8320)
//              t2t f16 32x88 @11840 (5632, aliases t1, live after C).
//              Total 20160 B -> 8 blocks/CU.

typedef float   f4 __attribute__((ext_vector_type(4)));
typedef float   f2 __attribute__((ext_vector_type(2)));
typedef _Float16 h2 __attribute__((ext_vector_type(2)));

#define ACT_SB   160      // act row stride bytes (80 f16)
#define T1_OFF   11840
#define T1S4     20       // t1 stride in f4 units (80 words)
#define T2T_SB   176      // t2t row stride bytes (88 f16)
#define LDS_B    20160

static __device__ __forceinline__ h2 as_h2(unsigned u) {
    union { unsigned u; h2 h; } x; x.u = u; return x.h;
}
static __device__ __forceinline__ unsigned pkrtz_u32(float lo, float hi) {
    union { __fp16 __attribute__((ext_vector_type(2))) h; unsigned u; } x;
    x.h = __builtin_amdgcn_cvt_pkrtz(lo, hi);
    return x.u;
}
// packed-f16 leaky: max(x, 0.2*x)  (x>=0 -> x ; x<0 -> 0.2x)
static __device__ __forceinline__ unsigned leaky_pk(unsigned x, unsigned c02) {
    unsigned t, r;
    asm("v_pk_mul_f16 %0, %1, %2" : "=v"(t) : "v"(x), "v"(c02));
    asm("v_pk_max_f16 %0, %1, %2" : "=v"(r) : "v"(x), "v"(t));
    return r;
}

__global__ __launch_bounds__(256, 8) void afa_kernel(
    const float* __restrict__ x, const float* __restrict__ bias,
    const float* __restrict__ fup, const float* __restrict__ fdn,
    float* __restrict__ out)
{
    __shared__ __align__(16) unsigned char smem[LDS_B];
    f4* const t14 = (f4*)(smem + T1_OFF);

    const int tid   = threadIdx.x;
    const int blk   = blockIdx.x;
    const int plane = blk >> 6;
    const int tile  = blk & 63;
    const int ty = tile >> 3, tx = tile & 7;
    const bool edge = (tx == 7) || (ty == 7);

    float fr[24], gr[12];
    #pragma unroll
    for (int i = 0; i < 24; ++i) fr[i] = fup[i];
    #pragma unroll
    for (int i = 0; i < 12; ++i) gr[i] = fdn[i];

    // dot2 filter pairs: gpk[m] = (g[11-2m], g[10-2m])  -- NO sqrt2 here,
    // gpk is used by BOTH C and D; sqrt2 applied once in D's epilogue.
    h2 gpk[6];
    #pragma unroll
    for (int m = 0; m < 6; ++m) {
        h2 p;
        p.x = (_Float16)gr[11 - 2 * m];
        p.y = (_Float16)gr[10 - 2 * m];
        gpk[m] = p;
    }
    const unsigned c02 = 0x32663266u;   // (0.2h, 0.2h)

    // bias fold: up(x+b) = up(x) + b*s[k0u]*s[k0v], s[p]=sum_t f[p+4t]
    const float s0 = fr[0] + fr[4] + fr[8]  + fr[12] + fr[16] + fr[20];
    const float s1 = fr[1] + fr[5] + fr[9]  + fr[13] + fr[17] + fr[21];
    const float s2 = fr[2] + fr[6] + fr[10] + fr[14] + fr[18] + fr[22];
    const float s3 = fr[3] + fr[7] + fr[11] + fr[15] + fr[19] + fr[23];
    const float b  = bias[plane & 255];
    const f4 su4 = {s1, s2, s3, s0};              // s[(cc+1)&3]
    f4 bc[4];
    bc[0] = su4 * (b * s0);
    bc[1] = su4 * (b * s1);
    bc[2] = su4 * (b * s2);
    bc[3] = su4 * (b * s3);

    const int iy_base = 16 * ty + 1;
    const int ix_base = 16 * tx + 1;
    const float* xp = x + (size_t)plane * (128 * 128);

    // ---- A: horizontal upsample, direct global reads -> t1 (26 x 80) ----
    for (int task = tid; task < 260; task += 256) {
        const int r = task / 10, ug = task - r * 10;
        float xw[8];
        if (!edge) {
            const float* row = xp + (iy_base + r) * 128 + (ix_base + 2 * ug);
            #pragma unroll
            for (int m = 0; m < 8; ++m) xw[m] = row[m];
        } else {
            const int iy = min(iy_base + r, 127);
            const float* row = xp + iy * 128;
            const int ix0 = ix_base + 2 * ug;
            #pragma unroll
            for (int m = 0; m < 8; ++m) xw[m] = row[min(ix0 + m, 127)];
        }
        f4 res0, res1;
        #pragma unroll
        for (int du = 0; du < 8; ++du) {
            const int k0 = (du + 1) & 3;
            const int bb = ((du + 25 - k0) >> 2) - 1;
            float acc = 0.f;
            #pragma unroll
            for (int t = 0; t < 6; ++t) acc += fr[k0 + 4 * t] * xw[bb - t];
            if (du < 4) res0[du] = acc; else res1[du - 4] = acc;
        }
        t14[r * T1S4 + 2 * ug]     = res0;
        t14[r * T1S4 + 2 * ug + 1] = res1;
    }
    __syncthreads();

    // ---- B: vertical upsample + bias, pack f16, leaky in f16 -> act ----
    if (tid < 190) {
        const int vt8 = tid / 19, ut = tid - vt8 * 19;
        f4 w[8];
        #pragma unroll
        for (int m = 0; m < 8; ++m)
            w[m] = t14[(2 * vt8 + m) * T1S4 + ut];
        f2 wl[8], wh[8];
        #pragma unroll
        for (int m = 0; m < 8; ++m) {
            wl[m] = f2{w[m][0], w[m][1]};
            wh[m] = f2{w[m][2], w[m][3]};
        }
        #pragma unroll
        for (int dv = 0; dv < 8; ++dv) {
            const int row = 8 * vt8 + dv;
            if (row < 74) {
                const int k0 = (dv + 1) & 3;
                const int bb = 5 + ((dv + 1) >> 2);
                f2 al = {bc[k0][0], bc[k0][1]};
                f2 ah = {bc[k0][2], bc[k0][3]};
                #pragma unroll
                for (int t = 0; t < 6; ++t) {
                    al += fr[k0 + 4 * t] * wl[bb - t];
                    ah += fr[k0 + 4 * t] * wh[bb - t];
                }
                uint2 pp;
                pp.x = leaky_pk(pkrtz_u32(al[0], al[1]), c02);
                pp.y = leaky_pk(pkrtz_u32(ah[0], ah[1]), c02);
                *(uint2*)(smem + row * ACT_SB + 8 * ut) = pp;
            }
        }
    }
    __syncthreads();

    // ---- C: horizontal downsample via dot2 -> t2t f16 [o][v] (transposed) ----
    {
        // batch 1: rows 0..63, all 256 threads
        const int v = tid & 63, otg = tid >> 6;
        {
            const unsigned* ar = (const unsigned*)(smem + v * ACT_SB + 32 * otg);
            uint4 q0 = *(const uint4*)(ar);
            uint4 q1 = *(const uint4*)(ar + 4);
            uint4 q2 = *(const uint4*)(ar + 8);
            const unsigned dl = ar[12];
            unsigned d[13] = {q0.x,q0.y,q0.z,q0.w, q1.x,q1.y,q1.z,q1.w,
                              q2.x,q2.y,q2.z,q2.w, dl};
            #pragma unroll
            for (int i = 0; i < 8; ++i) {
                float acc = 0.f;
                #pragma unroll
                for (int m = 0; m < 6; ++m)
                    acc = __builtin_amdgcn_fdot2(as_h2(d[i + m]), gpk[m], acc, false);
                _Float16 hv = (_Float16)acc;
                *(_Float16*)(smem + T1_OFF + (8*otg + i) * T2T_SB + 2*v) = hv;
            }
        }
        // batch 2: rows 64..73
        if (tid < 64) {
            const int otg2 = tid >> 4, vr = tid & 15;
            if (vr < 10) {
                const int v2 = 64 + vr;
                const unsigned* ar = (const unsigned*)(smem + v2 * ACT_SB + 32 * otg2);
                uint4 q0 = *(const uint4*)(ar);
                uint4 q1 = *(const uint4*)(ar + 4);
                uint4 q2 = *(const uint4*)(ar + 8);
                const unsigned dl = ar[12];
                unsigned d[13] = {q0.x,q0.y,q0.z,q0.w, q1.x,q1.y,q1.z,q1.w,
                                  q2.x,q2.y,q2.z,q2.w, dl};
                #pragma unroll
                for (int i = 0; i < 8; ++i) {
                    float acc = 0.f;
                    #pragma unroll
                    for (int m = 0; m < 6; ++m)
                        acc = __builtin_amdgcn_fdot2(as_h2(d[i + m]), gpk[m], acc, false);
                    _Float16 hv = (_Float16)acc;
                    *(_Float16*)(smem + T1_OFF + (8*otg2 + i) * T2T_SB + 2*v2) = hv;
                }
            }
        }
    }
    __syncthreads();

    // ---- D: vertical downsample via dot2, *sqrt2, store to global ----
    {
        const int oy0 = ty * 32, ox0 = tx * 32;
        float* op = out + (size_t)plane * (236 * 236);
        const int ox = tid & 31, g = tid >> 5;
        const unsigned* tr = (const unsigned*)(smem + T1_OFF + ox * T2T_SB + 16 * g);
        uint4 q0 = *(const uint4*)(tr);
        uint4 q1 = *(const uint4*)(tr + 4);
        const unsigned dl = tr[8];
        unsigned d[9] = {q0.x, q0.y, q0.z, q0.w, q1.x, q1.y, q1.z, q1.w, dl};
        const int oxg = ox0 + ox;
        if (!edge) {
            #pragma unroll
            for (int dv = 0; dv < 4; ++dv) {
                float acc = 0.f;
                #pragma unroll
                for (int m = 0; m < 6; ++m)
                    acc = __builtin_amdgcn_fdot2(as_h2(d[dv + m]), gpk[m], acc, false);
                op[(oy0 + 4 * g + dv) * 236 + oxg] = acc * 1.4142135623730951f;
            }
        } else {
            #pragma unroll
            for (int dv = 0; dv < 4; ++dv) {
                float acc = 0.f;
                #pragma unroll
                for (int m = 0; m < 6; ++m)
                    acc = __builtin_amdgcn_fdot2(as_h2(d[dv + m]), gpk[m], acc, false);
                const int oy = oy0 + 4 * g + dv;
                if (oy < 236 && oxg < 236)
                    op[oy * 236 + oxg] = acc * 1.4142135623730951f;
            }
        }
    }
}

extern "C" void kernel_launch(void* const* d_in, const int* in_sizes, int n_in,
                              void* d_out, int out_size, void* d_ws, size_t ws_size,
                              hipStream_t stream) {
    const float* x    = (const float*)d_in[0];
    const float* bias = (const float*)d_in[1];
    const float* fup  = (const float*)d_in[2];
    const float* fdn  = (const float*)d_in[3];
    float* out = (float*)d_out;

    dim3 grid(1024 * 64);
    dim3 block(256);
    afa_kernel<<<grid, block, 0, stream>>>(x, bias, fup, fdn, out);
}